// Round 1
// baseline (271.038 us; speedup 1.0000x reference)
//
#include <hip/hip_runtime.h>
#include <hip/hip_bf16.h>
#include <math.h>

#define BB 8
#define DD 4096
#define NH 32
#define NKV 8
#define HD 128
#define KVL 4096
#define NSPLIT 16
#define CHUNK (KVL / NSPLIT)       // 256
#define SCALE 0.08838834764831845f // 1/sqrt(128)

// workspace layout (float offsets)
#define OFF_QRAW  0
#define OFF_KRAW  (OFF_QRAW + BB*NH*HD)      // 32768
#define OFF_VRAW  (OFF_KRAW + BB*NKV*HD)     // 40960
#define OFF_QROPE (OFF_VRAW + BB*NKV*HD)     // 49152
#define OFF_KROPE (OFF_QROPE + BB*NH*HD)     // 81920
#define OFF_PART  (OFF_KROPE + BB*NKV*HD)    // 90112
#define PART_STRIDE 132
#define OFF_CTX   (OFF_PART + BB*NH*NSPLIT*PART_STRIDE) // 630784
// total floats = 630784 + 32768 = 663552  (~2.65 MB of d_ws)

// ---------------- K1: fused QKV projection (wave per output row, 8-batch accum)
__global__ __launch_bounds__(256) void k_qkv(
    const float* __restrict__ hs,
    const float* __restrict__ Wq, const float* __restrict__ bq,
    const float* __restrict__ Wk, const float* __restrict__ bk,
    const float* __restrict__ Wv, const float* __restrict__ bv,
    float* __restrict__ ws)
{
    const int wid  = threadIdx.x >> 6;
    const int lane = threadIdx.x & 63;
    const int row  = blockIdx.x * 4 + wid;   // 0..6143
    const float* W; const float* bias; float* dst; int dstride; int r;
    if (row < 4096)      { W = Wq; bias = bq; r = row;        dst = ws + OFF_QRAW; dstride = NH*HD; }
    else if (row < 5120) { W = Wk; bias = bk; r = row - 4096; dst = ws + OFF_KRAW; dstride = NKV*HD; }
    else                 { W = Wv; bias = bv; r = row - 5120; dst = ws + OFF_VRAW; dstride = NKV*HD; }

    const float4* Wr = (const float4*)(W + (size_t)r * DD);
    float acc[BB];
    #pragma unroll
    for (int b = 0; b < BB; ++b) acc[b] = 0.f;

    for (int it = 0; it < DD/256; ++it) {      // 16 iterations
        const int idx = it*64 + lane;
        const float4 w4 = Wr[idx];
        #pragma unroll
        for (int b = 0; b < BB; ++b) {
            const float4 h4 = ((const float4*)(hs + (size_t)b*DD))[idx];
            acc[b] = fmaf(w4.x, h4.x, fmaf(w4.y, h4.y, fmaf(w4.z, h4.z, fmaf(w4.w, h4.w, acc[b]))));
        }
    }
    #pragma unroll
    for (int b = 0; b < BB; ++b) {
        float v = acc[b];
        #pragma unroll
        for (int off = 32; off; off >>= 1) v += __shfl_xor(v, off, 64);
        acc[b] = v;
    }
    if (lane == 0) {
        const float bb = bias[r];
        #pragma unroll
        for (int b = 0; b < BB; ++b) dst[(size_t)b*dstride + r] = acc[b] + bb;
    }
}

// ---------------- K2: RoPE on q (8x32 heads) and k_new (8x8 heads)
__global__ __launch_bounds__(256) void k_rope(const int* __restrict__ posp, float* __restrict__ ws)
{
    const int gid = blockIdx.x * 256 + threadIdx.x;   // < 320*128 = 40960
    const int i  = gid & (HD-1);
    const int hh = gid >> 7;                          // head index 0..319
    const double pos = (double)posp[0];
    const int j = i & 63;
    const double ang = pos * pow(10000.0, -(double)j / 64.0);
    const float c = (float)cos(ang), s = (float)sin(ang);
    const bool isq = hh < BB*NH;
    const int hl = isq ? hh : hh - BB*NH;
    const float* src = ws + (isq ? OFF_QRAW  : OFF_KRAW)  + hl * HD;
    float* dstp      = ws + (isq ? OFF_QROPE : OFF_KROPE) + hl * HD;
    const float x = src[i];
    const float o = (i < 64) ? -src[i + 64] : src[i - 64];
    dstp[i] = fmaf(x, c, o * s);
}

// ---------------- K3: flash-decode split  (block = 256 thr, per (b,h,split))
__global__ __launch_bounds__(256) void k_attn(
    const float* __restrict__ Kc, const float* __restrict__ Vc,
    float* __restrict__ ws)
{
    __shared__ float sc[CHUNK + 1];
    __shared__ float red[4];
    __shared__ float ctxs[HD];

    const int pair  = blockIdx.x / NSPLIT;   // b*32 + h
    const int split = blockIdx.x % NSPLIT;
    const int b = pair >> 5, h = pair & 31;
    const int tid = threadIdx.x, wid = tid >> 6, lane = tid & 63;
    const int sub = lane >> 5, l32 = lane & 31;

    const float* q = ws + OFF_QROPE + pair * HD;
    const size_t base = ((size_t)pair * KVL + (size_t)split * CHUNK) * HD;
    const float* Kp = Kc + base;
    const float* Vp = Vc + base;
    const bool extra = (split == NSPLIT - 1);

    const float4 q4 = ((const float4*)q)[l32];

    // phase A: scores — each wave does 2 positions per iteration (1KB coalesced)
    #pragma unroll 4
    for (int it = 0; it < 32; ++it) {
        const int p = wid*64 + it*2 + sub;
        const float4 k4 = ((const float4*)(Kp + (size_t)p * HD))[l32];
        float v = q4.x*k4.x + q4.y*k4.y + q4.z*k4.z + q4.w*k4.w;
        #pragma unroll
        for (int off = 16; off; off >>= 1) v += __shfl_xor(v, off, 64);
        if (l32 == 0) sc[p] = v * SCALE;
    }
    if (extra && wid == 0) {   // new token (GQA: head h uses kv-head h/4)
        const float* kn = ws + OFF_KROPE + (b*NKV + (h>>2)) * HD;
        const float4 k4 = ((const float4*)kn)[l32];
        float v = q4.x*k4.x + q4.y*k4.y + q4.z*k4.z + q4.w*k4.w;
        #pragma unroll
        for (int off = 16; off; off >>= 1) v += __shfl_xor(v, off, 64);
        if (lane == 0) sc[CHUNK] = v * SCALE;
    }
    __syncthreads();

    const int cnt = CHUNK + (extra ? 1 : 0);
    // block max
    float m = -1e30f;
    for (int p2 = tid; p2 < cnt; p2 += 256) m = fmaxf(m, sc[p2]);
    #pragma unroll
    for (int off = 32; off; off >>= 1) m = fmaxf(m, __shfl_xor(m, off, 64));
    if (lane == 0) red[wid] = m;
    __syncthreads();
    m = fmaxf(fmaxf(red[0], red[1]), fmaxf(red[2], red[3]));
    __syncthreads();
    // exp + block sum
    float lsum = 0.f;
    for (int p2 = tid; p2 < cnt; p2 += 256) {
        const float e = expf(sc[p2] - m);
        sc[p2] = e;
        lsum += e;
    }
    #pragma unroll
    for (int off = 32; off; off >>= 1) lsum += __shfl_xor(lsum, off, 64);
    if (lane == 0) red[wid] = lsum;
    __syncthreads();
    const float L = red[0] + red[1] + red[2] + red[3];

    // phase C: unnormalized ctx partial
    const int d = tid & (HD-1);
    const int half = tid >> 7;
    float acc = 0.f;
    const float* Vh = Vp + (size_t)half * (CHUNK/2) * HD;
    for (int i2 = 0; i2 < CHUNK/2; ++i2)
        acc = fmaf(sc[half*(CHUNK/2) + i2], Vh[(size_t)i2 * HD + d], acc);
    if (extra && half == 0) {
        const float* vn = ws + OFF_VRAW + (b*NKV + (h>>2)) * HD;
        acc = fmaf(sc[CHUNK], vn[d], acc);
    }
    if (half == 0) ctxs[d] = acc;
    __syncthreads();
    if (half == 1) ctxs[d] += acc;
    __syncthreads();

    float* pp = ws + OFF_PART + ((size_t)pair * NSPLIT + split) * PART_STRIDE;
    if (tid < HD)            pp[tid]    = ctxs[tid];
    else if (tid == HD)      pp[HD]     = m;
    else if (tid == HD + 1)  pp[HD + 1] = L;
}

// ---------------- K4: combine splits (block per (b,h))
__global__ __launch_bounds__(128) void k_combine(float* __restrict__ ws)
{
    const int pair = blockIdx.x;
    const int d = threadIdx.x;
    const float* pp = ws + OFF_PART + (size_t)pair * NSPLIT * PART_STRIDE;
    __shared__ float sm[NSPLIT], sl[NSPLIT];
    if (d < NSPLIT) { sm[d] = pp[d*PART_STRIDE + HD]; sl[d] = pp[d*PART_STRIDE + HD + 1]; }
    __syncthreads();
    float M = -1e30f;
    #pragma unroll
    for (int s = 0; s < NSPLIT; ++s) M = fmaxf(M, sm[s]);
    float L = 0.f, acc = 0.f;
    #pragma unroll
    for (int s = 0; s < NSPLIT; ++s) {
        const float w = expf(sm[s] - M);
        L += sl[s] * w;
        acc += pp[s*PART_STRIDE + d] * w;
    }
    ws[OFF_CTX + pair*HD + d] = acc / L;
}

// ---------------- K5: output projection (wave per row, 8-batch accum)
__global__ __launch_bounds__(256) void k_oproj(
    const float* __restrict__ Wo, const float* __restrict__ ws, float* __restrict__ out)
{
    const int wid  = threadIdx.x >> 6;
    const int lane = threadIdx.x & 63;
    const int row  = blockIdx.x * 4 + wid;   // 0..4095
    const float4* Wr = (const float4*)(Wo + (size_t)row * DD);
    const float* ctx = ws + OFF_CTX;
    float acc[BB];
    #pragma unroll
    for (int b = 0; b < BB; ++b) acc[b] = 0.f;
    for (int it = 0; it < DD/256; ++it) {
        const int idx = it*64 + lane;
        const float4 w4 = Wr[idx];
        #pragma unroll
        for (int b = 0; b < BB; ++b) {
            const float4 h4 = ((const float4*)(ctx + (size_t)b*DD))[idx];
            acc[b] = fmaf(w4.x, h4.x, fmaf(w4.y, h4.y, fmaf(w4.z, h4.z, fmaf(w4.w, h4.w, acc[b]))));
        }
    }
    #pragma unroll
    for (int b = 0; b < BB; ++b) {
        float v = acc[b];
        #pragma unroll
        for (int off = 32; off; off >>= 1) v += __shfl_xor(v, off, 64);
        if (lane == 0) out[(size_t)b*DD + row] = v;
    }
}

extern "C" void kernel_launch(void* const* d_in, const int* in_sizes, int n_in,
                              void* d_out, int out_size, void* d_ws, size_t ws_size,
                              hipStream_t stream)
{
    const float* hs  = (const float*)d_in[0];
    const float* pk  = (const float*)d_in[1];
    const float* pv  = (const float*)d_in[2];
    const float* Wq  = (const float*)d_in[3];
    const float* bq  = (const float*)d_in[4];
    const float* Wk  = (const float*)d_in[5];
    const float* bk  = (const float*)d_in[6];
    const float* Wv  = (const float*)d_in[7];
    const float* bv  = (const float*)d_in[8];
    const float* Wo  = (const float*)d_in[9];
    const int*   pos = (const int*)d_in[10];
    float* out = (float*)d_out;
    float* ws  = (float*)d_ws;

    k_qkv   <<<6144/4,           256, 0, stream>>>(hs, Wq, bq, Wk, bk, Wv, bv, ws);
    k_rope  <<<(BB*(NH+NKV)*HD)/256, 256, 0, stream>>>(pos, ws);
    k_attn  <<<BB*NH*NSPLIT,     256, 0, stream>>>(pk, pv, ws);
    k_combine<<<BB*NH,           128, 0, stream>>>(ws);
    k_oproj <<<4096/4,           256, 0, stream>>>(Wo, ws, out);
}

// Round 2
// 268.681 us; speedup vs baseline: 1.0088x; 1.0088x over previous
//
#include <hip/hip_runtime.h>
#include <hip/hip_bf16.h>
#include <math.h>

#define BB 8
#define DD 4096
#define NHQ 32
#define NKV 8
#define HD 128
#define KVL 4096
#define NSPLIT 32
#define CHUNK (KVL / NSPLIT)       // 128
#define SCALE 0.08838834764831845f // 1/sqrt(128)

// workspace layout (float offsets)
#define OFF_QROPE 0                           // 32768 floats
#define OFF_KROPE (OFF_QROPE + BB*NHQ*HD)     // 32768
#define OFF_VRAW  (OFF_KROPE + BB*NKV*HD)     // 40960
#define OFF_PART  (OFF_VRAW  + BB*NKV*HD)     // 49152
#define PART_STRIDE 132
#define OFF_CTX   (OFF_PART + BB*NHQ*NSPLIT*PART_STRIDE)
// total ~ 4.7 MB of d_ws

// ---------------- K1: fused QKV projection + RoPE
// wave computes the row PAIR (r, r+64) within one head so the rotary mix is
// in-register; 8 batch accumulators per row; each weight row fetched once.
__global__ __launch_bounds__(256) void k_qkv(
    const float* __restrict__ hs,
    const float* __restrict__ Wq, const float* __restrict__ bq,
    const float* __restrict__ Wk, const float* __restrict__ bk,
    const float* __restrict__ Wv, const float* __restrict__ bv,
    const int* __restrict__ posp,
    float* __restrict__ ws)
{
    const int wid  = threadIdx.x >> 6;
    const int lane = threadIdx.x & 63;
    const int w    = blockIdx.x * 4 + wid;   // 0..3071 wave-tasks

    const float* W; const float* bias; float* dst; int dstride; int r1; int i; bool rope;
    if (w < 2048) {                 // q rows: 32 heads x (64 pairs)
        const int h = w >> 6; i = w & 63; r1 = h*HD + i;
        W = Wq; bias = bq; dst = ws + OFF_QROPE; dstride = NHQ*HD; rope = true;
    } else if (w < 2560) {          // k rows: 8 heads x 64 pairs
        const int w2 = w - 2048; const int h = w2 >> 6; i = w2 & 63; r1 = h*HD + i;
        W = Wk; bias = bk; dst = ws + OFF_KROPE; dstride = NKV*HD; rope = true;
    } else {                        // v rows: 8 heads x 64 pairs (no rope)
        const int w3 = w - 2560; const int h = w3 >> 6; i = w3 & 63; r1 = h*HD + i;
        W = Wv; bias = bv; dst = ws + OFF_VRAW; dstride = NKV*HD; rope = false;
    }
    const int r2 = r1 + 64;

    // f64 rope angle (wave-uniform); overlaps with the load loop below
    const double pos = (double)posp[0];
    const double ang = pos * pow(10000.0, -(double)i / 64.0);
    const float c = (float)cos(ang), s = (float)sin(ang);

    const float4* WrA = (const float4*)(W + (size_t)r1 * DD);
    const float4* WrB = (const float4*)(W + (size_t)r2 * DD);
    const float4* H   = (const float4*)hs;

    float accA[BB], accB[BB];
    #pragma unroll
    for (int b = 0; b < BB; ++b) { accA[b] = 0.f; accB[b] = 0.f; }

    for (int it = 0; it < DD/256; ++it) {      // 16 iterations
        const int idx = it*64 + lane;
        const float4 wa = WrA[idx];
        const float4 wb = WrB[idx];
        #pragma unroll
        for (int b = 0; b < BB; ++b) {
            const float4 h4 = H[b*(DD/4) + idx];
            accA[b] = fmaf(wa.x, h4.x, fmaf(wa.y, h4.y, fmaf(wa.z, h4.z, fmaf(wa.w, h4.w, accA[b]))));
            accB[b] = fmaf(wb.x, h4.x, fmaf(wb.y, h4.y, fmaf(wb.z, h4.z, fmaf(wb.w, h4.w, accB[b]))));
        }
    }
    #pragma unroll
    for (int b = 0; b < BB; ++b) {
        float va = accA[b], vb = accB[b];
        #pragma unroll
        for (int off = 32; off; off >>= 1) {
            va += __shfl_xor(va, off, 64);
            vb += __shfl_xor(vb, off, 64);
        }
        accA[b] = va; accB[b] = vb;
    }
    if (lane == 0) {
        const float b1 = bias[r1], b2 = bias[r2];
        #pragma unroll
        for (int b = 0; b < BB; ++b) {
            const float a1 = accA[b] + b1;
            const float a2 = accB[b] + b2;
            float o1, o2;
            if (rope) { o1 = fmaf(a1, c, -a2*s); o2 = fmaf(a2, c, a1*s); }
            else      { o1 = a1;                 o2 = a2; }
            dst[(size_t)b*dstride + r1] = o1;
            dst[(size_t)b*dstride + r2] = o2;
        }
    }
}

// ---------------- K2: single-pass flash-decode, one wave per (pair, split)
// half-wave (32 lanes) processes one KV row per iteration: 512B K + 512B V,
// online softmax in registers, no LDS, no barriers.
__global__ __launch_bounds__(256) void k_attn(
    const float* __restrict__ Kc, const float* __restrict__ Vc,
    float* __restrict__ ws)
{
    const int wid  = threadIdx.x >> 6;
    const int lane = threadIdx.x & 63;
    const int sub  = lane >> 5, l32 = lane & 31;
    const int task  = blockIdx.x * 4 + wid;     // 0..8191
    const int pair  = task >> 5;                // b*32 + h
    const int split = task & (NSPLIT - 1);
    const int b = pair >> 5, h = pair & 31;

    const float4 q4 = ((const float4*)(ws + OFF_QROPE + (size_t)pair * HD))[l32];
    const size_t base = ((size_t)pair * KVL + (size_t)split * CHUNK) * HD;
    const float4* Kp = (const float4*)(Kc + base);
    const float4* Vp = (const float4*)(Vc + base);

    float m = -1e30f, l = 0.f;
    float4 acc = {0.f, 0.f, 0.f, 0.f};

    #pragma unroll 4
    for (int it = 0; it < CHUNK/2; ++it) {
        const int p = it*2 + sub;
        const float4 k4 = Kp[p*32 + l32];
        const float4 v4 = Vp[p*32 + l32];
        float sv = fmaf(q4.x, k4.x, fmaf(q4.y, k4.y, fmaf(q4.z, k4.z, q4.w*k4.w)));
        #pragma unroll
        for (int off = 16; off; off >>= 1) sv += __shfl_xor(sv, off, 64);
        sv *= SCALE;
        if (sv > m) {
            const float r_ = __expf(m - sv);
            l *= r_; acc.x *= r_; acc.y *= r_; acc.z *= r_; acc.w *= r_;
            m = sv;
        }
        const float pw = __expf(sv - m);
        l += pw;
        acc.x = fmaf(pw, v4.x, acc.x);
        acc.y = fmaf(pw, v4.y, acc.y);
        acc.z = fmaf(pw, v4.z, acc.z);
        acc.w = fmaf(pw, v4.w, acc.w);
    }

    // append the new token (GQA: head h uses kv-head h/4) on the last split
    if (split == NSPLIT - 1 && sub == 0) {
        const float4 k4 = ((const float4*)(ws + OFF_KROPE + (size_t)(b*NKV + (h>>2)) * HD))[l32];
        const float4 v4 = ((const float4*)(ws + OFF_VRAW  + (size_t)(b*NKV + (h>>2)) * HD))[l32];
        float sv = fmaf(q4.x, k4.x, fmaf(q4.y, k4.y, fmaf(q4.z, k4.z, q4.w*k4.w)));
        #pragma unroll
        for (int off = 16; off; off >>= 1) sv += __shfl_xor(sv, off, 64);
        sv *= SCALE;
        if (sv > m) {
            const float r_ = __expf(m - sv);
            l *= r_; acc.x *= r_; acc.y *= r_; acc.z *= r_; acc.w *= r_;
            m = sv;
        }
        const float pw = __expf(sv - m);
        l += pw;
        acc.x = fmaf(pw, v4.x, acc.x);
        acc.y = fmaf(pw, v4.y, acc.y);
        acc.z = fmaf(pw, v4.z, acc.z);
        acc.w = fmaf(pw, v4.w, acc.w);
    }

    // merge the two half-wave online states
    const float M  = fmaxf(m, __shfl_xor(m, 32, 64));
    const float r_ = __expf(m - M);
    l *= r_; acc.x *= r_; acc.y *= r_; acc.z *= r_; acc.w *= r_;
    l     += __shfl_xor(l,     32, 64);
    acc.x += __shfl_xor(acc.x, 32, 64);
    acc.y += __shfl_xor(acc.y, 32, 64);
    acc.z += __shfl_xor(acc.z, 32, 64);
    acc.w += __shfl_xor(acc.w, 32, 64);

    if (sub == 0) {
        float* pp = ws + OFF_PART + ((size_t)pair * NSPLIT + split) * PART_STRIDE;
        ((float4*)pp)[l32] = acc;
        if (l32 == 0) { pp[HD] = M; pp[HD+1] = l; }
    }
}

// ---------------- K3: combine splits (block per (b,h))
__global__ __launch_bounds__(128) void k_combine(float* __restrict__ ws)
{
    const int pair = blockIdx.x;
    const int d = threadIdx.x;
    const float* pp = ws + OFF_PART + (size_t)pair * NSPLIT * PART_STRIDE;
    __shared__ float sm[NSPLIT], sl[NSPLIT];
    if (d < NSPLIT) { sm[d] = pp[d*PART_STRIDE + HD]; sl[d] = pp[d*PART_STRIDE + HD + 1]; }
    __syncthreads();
    float M = -1e30f;
    #pragma unroll
    for (int s = 0; s < NSPLIT; ++s) M = fmaxf(M, sm[s]);
    float L = 0.f, acc = 0.f;
    #pragma unroll
    for (int s = 0; s < NSPLIT; ++s) {
        const float w = expf(sm[s] - M);
        L += sl[s] * w;
        acc = fmaf(pp[s*PART_STRIDE + d], w, acc);
    }
    ws[OFF_CTX + (size_t)pair*HD + d] = acc / L;
}

// ---------------- K4: output projection (wave per row, 8-batch accum)
__global__ __launch_bounds__(256) void k_oproj(
    const float* __restrict__ Wo, const float* __restrict__ ws, float* __restrict__ out)
{
    const int wid  = threadIdx.x >> 6;
    const int lane = threadIdx.x & 63;
    const int row  = blockIdx.x * 4 + wid;   // 0..4095
    const float4* Wr = (const float4*)(Wo + (size_t)row * DD);
    const float4* C  = (const float4*)(ws + OFF_CTX);
    float acc[BB];
    #pragma unroll
    for (int b = 0; b < BB; ++b) acc[b] = 0.f;
    for (int it = 0; it < DD/256; ++it) {
        const int idx = it*64 + lane;
        const float4 w4 = Wr[idx];
        #pragma unroll
        for (int b = 0; b < BB; ++b) {
            const float4 h4 = C[b*(DD/4) + idx];
            acc[b] = fmaf(w4.x, h4.x, fmaf(w4.y, h4.y, fmaf(w4.z, h4.z, fmaf(w4.w, h4.w, acc[b]))));
        }
    }
    #pragma unroll
    for (int b = 0; b < BB; ++b) {
        float v = acc[b];
        #pragma unroll
        for (int off = 32; off; off >>= 1) v += __shfl_xor(v, off, 64);
        if (lane == 0) out[(size_t)b*DD + row] = v;
    }
}

extern "C" void kernel_launch(void* const* d_in, const int* in_sizes, int n_in,
                              void* d_out, int out_size, void* d_ws, size_t ws_size,
                              hipStream_t stream)
{
    const float* hs  = (const float*)d_in[0];
    const float* pk  = (const float*)d_in[1];
    const float* pv  = (const float*)d_in[2];
    const float* Wq  = (const float*)d_in[3];
    const float* bq  = (const float*)d_in[4];
    const float* Wk  = (const float*)d_in[5];
    const float* bk  = (const float*)d_in[6];
    const float* Wv  = (const float*)d_in[7];
    const float* bv  = (const float*)d_in[8];
    const float* Wo  = (const float*)d_in[9];
    const int*   pos = (const int*)d_in[10];
    float* out = (float*)d_out;
    float* ws  = (float*)d_ws;

    k_qkv    <<<3072/4,      256, 0, stream>>>(hs, Wq, bq, Wk, bk, Wv, bv, pos, ws);
    k_attn   <<<BB*NHQ*NSPLIT/4, 256, 0, stream>>>(pk, pv, ws);
    k_combine<<<BB*NHQ,      128, 0, stream>>>(ws);
    k_oproj  <<<4096/4,      256, 0, stream>>>(Wo, ws, out);
}

// Round 4
// 258.781 us; speedup vs baseline: 1.0474x; 1.0383x over previous
//
#include <hip/hip_runtime.h>
#include <hip/hip_bf16.h>
#include <math.h>

#define BB 8
#define DD 4096
#define NHQ 32
#define NKV 8
#define HD 128
#define KVL 4096
#define NSPLIT 32
#define CHUNK (KVL / NSPLIT)       // 128
#define SCALE 0.08838834764831845f // 1/sqrt(128)

// workspace layout (float offsets)
#define OFF_QROPE 0                           // 32768 floats
#define OFF_KROPE (OFF_QROPE + BB*NHQ*HD)     // 32768
#define OFF_VRAW  (OFF_KROPE + BB*NKV*HD)     // 40960
#define OFF_PART  (OFF_VRAW  + BB*NKV*HD)     // 49152
#define PART_STRIDE 132
#define OFF_CTX   (OFF_PART + BB*NHQ*NSPLIT*PART_STRIDE)

typedef float f32x4 __attribute__((ext_vector_type(4)));

__device__ __forceinline__ float4 ntload4(const float4* p) {
    f32x4 v = __builtin_nontemporal_load((const f32x4*)p);
    return make_float4(v.x, v.y, v.z, v.w);
}

// ---------------- K1: fused QKV projection + RoPE
__global__ __launch_bounds__(256) void k_qkv(
    const float* __restrict__ hs,
    const float* __restrict__ Wq, const float* __restrict__ bq,
    const float* __restrict__ Wk, const float* __restrict__ bk,
    const float* __restrict__ Wv, const float* __restrict__ bv,
    const int* __restrict__ posp,
    float* __restrict__ ws)
{
    const int wid  = threadIdx.x >> 6;
    const int lane = threadIdx.x & 63;
    const int w    = blockIdx.x * 4 + wid;   // 0..3071 wave-tasks

    const float* W; const float* bias; float* dst; int dstride; int r1; int i; bool rope;
    if (w < 2048) {                 // q rows: 32 heads x 64 pairs
        const int h = w >> 6; i = w & 63; r1 = h*HD + i;
        W = Wq; bias = bq; dst = ws + OFF_QROPE; dstride = NHQ*HD; rope = true;
    } else if (w < 2560) {          // k rows: 8 heads x 64 pairs
        const int w2 = w - 2048; const int h = w2 >> 6; i = w2 & 63; r1 = h*HD + i;
        W = Wk; bias = bk; dst = ws + OFF_KROPE; dstride = NKV*HD; rope = true;
    } else {                        // v rows: 8 heads x 64 pairs (no rope)
        const int w3 = w - 2560; const int h = w3 >> 6; i = w3 & 63; r1 = h*HD + i;
        W = Wv; bias = bv; dst = ws + OFF_VRAW; dstride = NKV*HD; rope = false;
    }
    const int r2 = r1 + 64;

    const double pos = (double)posp[0];
    const double ang = pos * pow(10000.0, -(double)i / 64.0);
    const float c = (float)cos(ang), s = (float)sin(ang);

    const float4* WrA = (const float4*)(W + (size_t)r1 * DD);
    const float4* WrB = (const float4*)(W + (size_t)r2 * DD);
    const float4* H   = (const float4*)hs;

    float accA[BB], accB[BB];
    #pragma unroll
    for (int b = 0; b < BB; ++b) { accA[b] = 0.f; accB[b] = 0.f; }

    for (int it = 0; it < DD/256; ++it) {      // 16 iterations
        const int idx = it*64 + lane;
        const float4 wa = ntload4(&WrA[idx]);
        const float4 wb = ntload4(&WrB[idx]);
        #pragma unroll
        for (int b = 0; b < BB; ++b) {
            const float4 h4 = H[b*(DD/4) + idx];
            accA[b] = fmaf(wa.x, h4.x, fmaf(wa.y, h4.y, fmaf(wa.z, h4.z, fmaf(wa.w, h4.w, accA[b]))));
            accB[b] = fmaf(wb.x, h4.x, fmaf(wb.y, h4.y, fmaf(wb.z, h4.z, fmaf(wb.w, h4.w, accB[b]))));
        }
    }
    #pragma unroll
    for (int b = 0; b < BB; ++b) {
        float va = accA[b], vb = accB[b];
        #pragma unroll
        for (int off = 32; off; off >>= 1) {
            va += __shfl_xor(va, off, 64);
            vb += __shfl_xor(vb, off, 64);
        }
        accA[b] = va; accB[b] = vb;
    }
    if (lane == 0) {
        const float b1 = bias[r1], b2 = bias[r2];
        #pragma unroll
        for (int b = 0; b < BB; ++b) {
            const float a1 = accA[b] + b1;
            const float a2 = accB[b] + b2;
            float o1, o2;
            if (rope) { o1 = fmaf(a1, c, -a2*s); o2 = fmaf(a2, c, a1*s); }
            else      { o1 = a1;                 o2 = a2; }
            dst[(size_t)b*dstride + r1] = o1;
            dst[(size_t)b*dstride + r2] = o2;
        }
    }
}

// ---------------- K2: branchless single-pass flash-decode
// one wave per (pair, split); 4 rows per iteration (two contiguous-1KB K loads
// + two V loads), branchless online softmax, no LDS, no barriers.
__global__ __launch_bounds__(256) void k_attn(
    const float* __restrict__ Kc, const float* __restrict__ Vc,
    float* __restrict__ ws)
{
    const int wid  = threadIdx.x >> 6;
    const int lane = threadIdx.x & 63;
    const int sub  = lane >> 5, l32 = lane & 31;
    const int task  = blockIdx.x * 4 + wid;     // 0..8191
    const int pair  = task >> 5;                // b*32 + h
    const int split = task & (NSPLIT - 1);
    const int b = pair >> 5, h = pair & 31;

    const float4 q4 = ((const float4*)(ws + OFF_QROPE + (size_t)pair * HD))[l32];
    const size_t base = ((size_t)pair * KVL + (size_t)split * CHUNK) * HD;
    const float4* Kp = (const float4*)(Kc + base);
    const float4* Vp = (const float4*)(Vc + base);

    float m = -1e30f, l = 0.f;
    float4 acc = {0.f, 0.f, 0.f, 0.f};

    #pragma unroll 2
    for (int it = 0; it < CHUNK/4; ++it) {      // 32 iterations, 4 rows each
        const int pa = it*4 + sub;              // rows {4it, 4it+1}
        const int pb = pa + 2;                  // rows {4it+2, 4it+3}
        const float4 ka = ntload4(&Kp[pa*32 + l32]);
        const float4 kb = ntload4(&Kp[pb*32 + l32]);
        const float4 va = ntload4(&Vp[pa*32 + l32]);
        const float4 vb = ntload4(&Vp[pb*32 + l32]);

        float sa = fmaf(q4.x, ka.x, fmaf(q4.y, ka.y, fmaf(q4.z, ka.z, q4.w*ka.w)));
        float sb = fmaf(q4.x, kb.x, fmaf(q4.y, kb.y, fmaf(q4.z, kb.z, q4.w*kb.w)));
        #pragma unroll
        for (int off = 16; off; off >>= 1) {
            sa += __shfl_xor(sa, off, 64);
            sb += __shfl_xor(sb, off, 64);
        }
        sa *= SCALE; sb *= SCALE;

        const float newm = fmaxf(fmaxf(m, sa), sb);   // v_max3
        const float r_ = __expf(m - newm);            // == 1.0 when m unchanged
        const float ea = __expf(sa - newm);
        const float eb = __expf(sb - newm);
        m = newm;
        l = fmaf(l, r_, ea + eb);
        acc.x = fmaf(acc.x, r_, fmaf(ea, va.x, eb*vb.x));
        acc.y = fmaf(acc.y, r_, fmaf(ea, va.y, eb*vb.y));
        acc.z = fmaf(acc.z, r_, fmaf(ea, va.z, eb*vb.z));
        acc.w = fmaf(acc.w, r_, fmaf(ea, va.w, eb*vb.w));
    }

    // append the new token (GQA: head h uses kv-head h/4) on the last split
    if (split == NSPLIT - 1 && sub == 0) {
        const float4 k4 = ((const float4*)(ws + OFF_KROPE + (size_t)(b*NKV + (h>>2)) * HD))[l32];
        const float4 v4 = ((const float4*)(ws + OFF_VRAW  + (size_t)(b*NKV + (h>>2)) * HD))[l32];
        float sv = fmaf(q4.x, k4.x, fmaf(q4.y, k4.y, fmaf(q4.z, k4.z, q4.w*k4.w)));
        #pragma unroll
        for (int off = 16; off; off >>= 1) sv += __shfl_xor(sv, off, 64);
        sv *= SCALE;
        const float newm = fmaxf(m, sv);
        const float r_ = __expf(m - newm);
        const float e  = __expf(sv - newm);
        m = newm;
        l = fmaf(l, r_, e);
        acc.x = fmaf(acc.x, r_, e*v4.x);
        acc.y = fmaf(acc.y, r_, e*v4.y);
        acc.z = fmaf(acc.z, r_, e*v4.z);
        acc.w = fmaf(acc.w, r_, e*v4.w);
    }

    // merge the two half-wave online states
    const float M  = fmaxf(m, __shfl_xor(m, 32, 64));
    const float r_ = __expf(m - M);
    l *= r_; acc.x *= r_; acc.y *= r_; acc.z *= r_; acc.w *= r_;
    l     += __shfl_xor(l,     32, 64);
    acc.x += __shfl_xor(acc.x, 32, 64);
    acc.y += __shfl_xor(acc.y, 32, 64);
    acc.z += __shfl_xor(acc.z, 32, 64);
    acc.w += __shfl_xor(acc.w, 32, 64);

    if (sub == 0) {
        float* pp = ws + OFF_PART + ((size_t)pair * NSPLIT + split) * PART_STRIDE;
        ((float4*)pp)[l32] = acc;
        if (l32 == 0) { pp[HD] = M; pp[HD+1] = l; }
    }
}

// ---------------- K3: combine splits (block per (b,h))
__global__ __launch_bounds__(128) void k_combine(float* __restrict__ ws)
{
    const int pair = blockIdx.x;
    const int d = threadIdx.x;
    const float* pp = ws + OFF_PART + (size_t)pair * NSPLIT * PART_STRIDE;
    __shared__ float sm[NSPLIT], sl[NSPLIT];
    if (d < NSPLIT) { sm[d] = pp[d*PART_STRIDE + HD]; sl[d] = pp[d*PART_STRIDE + HD + 1]; }
    __syncthreads();
    float M = -1e30f;
    #pragma unroll
    for (int s = 0; s < NSPLIT; ++s) M = fmaxf(M, sm[s]);
    float L = 0.f, acc = 0.f;
    #pragma unroll 8
    for (int s = 0; s < NSPLIT; ++s) {
        const float w = expf(sm[s] - M);
        L += sl[s] * w;
        acc = fmaf(pp[s*PART_STRIDE + d], w, acc);
    }
    ws[OFF_CTX + (size_t)pair*HD + d] = acc / L;
}

// ---------------- K4: output projection (wave per row, 8-batch accum)
__global__ __launch_bounds__(256) void k_oproj(
    const float* __restrict__ Wo, const float* __restrict__ ws, float* __restrict__ out)
{
    const int wid  = threadIdx.x >> 6;
    const int lane = threadIdx.x & 63;
    const int row  = blockIdx.x * 4 + wid;   // 0..4095
    const float4* Wr = (const float4*)(Wo + (size_t)row * DD);
    const float4* C  = (const float4*)(ws + OFF_CTX);
    float acc[BB];
    #pragma unroll
    for (int b = 0; b < BB; ++b) acc[b] = 0.f;
    for (int it = 0; it < DD/256; ++it) {
        const int idx = it*64 + lane;
        const float4 w4 = ntload4(&Wr[idx]);
        #pragma unroll
        for (int b = 0; b < BB; ++b) {
            const float4 h4 = C[b*(DD/4) + idx];
            acc[b] = fmaf(w4.x, h4.x, fmaf(w4.y, h4.y, fmaf(w4.z, h4.z, fmaf(w4.w, h4.w, acc[b]))));
        }
    }
    #pragma unroll
    for (int b = 0; b < BB; ++b) {
        float v = acc[b];
        #pragma unroll
        for (int off = 32; off; off >>= 1) v += __shfl_xor(v, off, 64);
        if (lane == 0) out[(size_t)b*DD + row] = v;
    }
}

extern "C" void kernel_launch(void* const* d_in, const int* in_sizes, int n_in,
                              void* d_out, int out_size, void* d_ws, size_t ws_size,
                              hipStream_t stream)
{
    const float* hs  = (const float*)d_in[0];
    const float* pk  = (const float*)d_in[1];
    const float* pv  = (const float*)d_in[2];
    const float* Wq  = (const float*)d_in[3];
    const float* bq  = (const float*)d_in[4];
    const float* Wk  = (const float*)d_in[5];
    const float* bk  = (const float*)d_in[6];
    const float* Wv  = (const float*)d_in[7];
    const float* bv  = (const float*)d_in[8];
    const float* Wo  = (const float*)d_in[9];
    const int*   pos = (const int*)d_in[10];
    float* out = (float*)d_out;
    float* ws  = (float*)d_ws;

    k_qkv    <<<3072/4,          256, 0, stream>>>(hs, Wq, bq, Wk, bk, Wv, bv, pos, ws);
    k_attn   <<<BB*NHQ*NSPLIT/4, 256, 0, stream>>>(pk, pv, ws);
    k_combine<<<BB*NHQ,          128, 0, stream>>>(ws);
    k_oproj  <<<4096/4,          256, 0, stream>>>(Wo, ws, out);
}

// Round 5
// 247.986 us; speedup vs baseline: 1.0930x; 1.0435x over previous
//
#include <hip/hip_runtime.h>
#include <hip/hip_bf16.h>
#include <math.h>

#define BB 8
#define DD 4096
#define NHQ 32
#define NKV 8
#define HD 128
#define KVL 4096
#define NSPLIT 32
#define CHUNK (KVL / NSPLIT)       // 128
#define SCALE 0.08838834764831845f // 1/sqrt(128)

// workspace layout (float offsets)
#define OFF_QROPE 0                           // 32768 floats
#define OFF_KROPE (OFF_QROPE + BB*NHQ*HD)     // 32768
#define OFF_VRAW  (OFF_KROPE + BB*NKV*HD)     // 40960
#define OFF_PART  (OFF_VRAW  + BB*NKV*HD)     // 49152
#define PART_STRIDE 132
#define OFF_CTX   (OFF_PART + BB*NHQ*NSPLIT*PART_STRIDE)

typedef float f32x4 __attribute__((ext_vector_type(4)));

__device__ __forceinline__ float4 ntload4(const float4* p) {
    f32x4 v = __builtin_nontemporal_load((const f32x4*)p);
    return make_float4(v.x, v.y, v.z, v.w);
}

// ---------------- K1: fused QKV projection + RoPE
__global__ __launch_bounds__(256) void k_qkv(
    const float* __restrict__ hs,
    const float* __restrict__ Wq, const float* __restrict__ bq,
    const float* __restrict__ Wk, const float* __restrict__ bk,
    const float* __restrict__ Wv, const float* __restrict__ bv,
    const int* __restrict__ posp,
    float* __restrict__ ws)
{
    const int wid  = threadIdx.x >> 6;
    const int lane = threadIdx.x & 63;
    const int w    = blockIdx.x * 4 + wid;   // 0..3071 wave-tasks

    const float* W; const float* bias; float* dst; int dstride; int r1; int i; bool rope;
    if (w < 2048) {                 // q rows: 32 heads x 64 pairs
        const int h = w >> 6; i = w & 63; r1 = h*HD + i;
        W = Wq; bias = bq; dst = ws + OFF_QROPE; dstride = NHQ*HD; rope = true;
    } else if (w < 2560) {          // k rows: 8 heads x 64 pairs
        const int w2 = w - 2048; const int h = w2 >> 6; i = w2 & 63; r1 = h*HD + i;
        W = Wk; bias = bk; dst = ws + OFF_KROPE; dstride = NKV*HD; rope = true;
    } else {                        // v rows: 8 heads x 64 pairs (no rope)
        const int w3 = w - 2560; const int h = w3 >> 6; i = w3 & 63; r1 = h*HD + i;
        W = Wv; bias = bv; dst = ws + OFF_VRAW; dstride = NKV*HD; rope = false;
    }
    const int r2 = r1 + 64;

    const double pos = (double)posp[0];
    const double ang = pos * pow(10000.0, -(double)i / 64.0);
    const float c = (float)cos(ang), s = (float)sin(ang);

    const float4* WrA = (const float4*)(W + (size_t)r1 * DD);
    const float4* WrB = (const float4*)(W + (size_t)r2 * DD);
    const float4* H   = (const float4*)hs;

    float accA[BB], accB[BB];
    #pragma unroll
    for (int b = 0; b < BB; ++b) { accA[b] = 0.f; accB[b] = 0.f; }

    for (int it = 0; it < DD/256; ++it) {      // 16 iterations
        const int idx = it*64 + lane;
        const float4 wa = ntload4(&WrA[idx]);
        const float4 wb = ntload4(&WrB[idx]);
        #pragma unroll
        for (int b = 0; b < BB; ++b) {
            const float4 h4 = H[b*(DD/4) + idx];
            accA[b] = fmaf(wa.x, h4.x, fmaf(wa.y, h4.y, fmaf(wa.z, h4.z, fmaf(wa.w, h4.w, accA[b]))));
            accB[b] = fmaf(wb.x, h4.x, fmaf(wb.y, h4.y, fmaf(wb.z, h4.z, fmaf(wb.w, h4.w, accB[b]))));
        }
    }
    #pragma unroll
    for (int b = 0; b < BB; ++b) {
        float va = accA[b], vb = accB[b];
        #pragma unroll
        for (int off = 32; off; off >>= 1) {
            va += __shfl_xor(va, off, 64);
            vb += __shfl_xor(vb, off, 64);
        }
        accA[b] = va; accB[b] = vb;
    }
    if (lane == 0) {
        const float b1 = bias[r1], b2 = bias[r2];
        #pragma unroll
        for (int b = 0; b < BB; ++b) {
            const float a1 = accA[b] + b1;
            const float a2 = accB[b] + b2;
            float o1, o2;
            if (rope) { o1 = fmaf(a1, c, -a2*s); o2 = fmaf(a2, c, a1*s); }
            else      { o1 = a1;                 o2 = a2; }
            dst[(size_t)b*dstride + r1] = o1;
            dst[(size_t)b*dstride + r2] = o2;
        }
    }
}

// ---------------- K2: branchless single-pass flash-decode, 8 rows/iteration
// one wave per (pair, split); per iteration: 4x1KB K loads + 4x1KB V loads
// (rows 8it..8it+7), 4 independent score-reduce chains, ONE shared rescale.
__global__ __launch_bounds__(256) void k_attn(
    const float* __restrict__ Kc, const float* __restrict__ Vc,
    float* __restrict__ ws)
{
    const int wid  = threadIdx.x >> 6;
    const int lane = threadIdx.x & 63;
    const int sub  = lane >> 5, l32 = lane & 31;
    const int task  = blockIdx.x * 4 + wid;     // 0..8191
    const int pair  = task >> 5;                // b*32 + h
    const int split = task & (NSPLIT - 1);
    const int b = pair >> 5, h = pair & 31;

    const float4 q4 = ((const float4*)(ws + OFF_QROPE + (size_t)pair * HD))[l32];
    const size_t base = ((size_t)pair * KVL + (size_t)split * CHUNK) * HD;
    const float4* Kp = (const float4*)(Kc + base);
    const float4* Vp = (const float4*)(Vc + base);

    float m = -1e30f, l = 0.f;
    float4 acc = {0.f, 0.f, 0.f, 0.f};

    for (int it = 0; it < CHUNK/8; ++it) {      // 16 iterations, 8 rows each
        const int r0 = it*8 + sub;
        const float4 k0 = ntload4(&Kp[(r0+0)*32 + l32]);
        const float4 k1 = ntload4(&Kp[(r0+2)*32 + l32]);
        const float4 k2 = ntload4(&Kp[(r0+4)*32 + l32]);
        const float4 k3 = ntload4(&Kp[(r0+6)*32 + l32]);
        const float4 v0 = ntload4(&Vp[(r0+0)*32 + l32]);
        const float4 v1 = ntload4(&Vp[(r0+2)*32 + l32]);
        const float4 v2 = ntload4(&Vp[(r0+4)*32 + l32]);
        const float4 v3 = ntload4(&Vp[(r0+6)*32 + l32]);

        float s0 = fmaf(q4.x, k0.x, fmaf(q4.y, k0.y, fmaf(q4.z, k0.z, q4.w*k0.w)));
        float s1 = fmaf(q4.x, k1.x, fmaf(q4.y, k1.y, fmaf(q4.z, k1.z, q4.w*k1.w)));
        float s2 = fmaf(q4.x, k2.x, fmaf(q4.y, k2.y, fmaf(q4.z, k2.z, q4.w*k2.w)));
        float s3 = fmaf(q4.x, k3.x, fmaf(q4.y, k3.y, fmaf(q4.z, k3.z, q4.w*k3.w)));
        #pragma unroll
        for (int off = 16; off; off >>= 1) {
            s0 += __shfl_xor(s0, off, 64);
            s1 += __shfl_xor(s1, off, 64);
            s2 += __shfl_xor(s2, off, 64);
            s3 += __shfl_xor(s3, off, 64);
        }
        s0 *= SCALE; s1 *= SCALE; s2 *= SCALE; s3 *= SCALE;

        const float newm = fmaxf(fmaxf(fmaxf(s0, s1), fmaxf(s2, s3)), m);
        const float r_ = __expf(m - newm);            // == 1.0 when m unchanged
        const float e0 = __expf(s0 - newm);
        const float e1 = __expf(s1 - newm);
        const float e2 = __expf(s2 - newm);
        const float e3 = __expf(s3 - newm);
        m = newm;
        l = fmaf(l, r_, (e0 + e1) + (e2 + e3));
        acc.x = fmaf(acc.x, r_, fmaf(e0, v0.x, e1*v1.x) + fmaf(e2, v2.x, e3*v3.x));
        acc.y = fmaf(acc.y, r_, fmaf(e0, v0.y, e1*v1.y) + fmaf(e2, v2.y, e3*v3.y));
        acc.z = fmaf(acc.z, r_, fmaf(e0, v0.z, e1*v1.z) + fmaf(e2, v2.z, e3*v3.z));
        acc.w = fmaf(acc.w, r_, fmaf(e0, v0.w, e1*v1.w) + fmaf(e2, v2.w, e3*v3.w));
    }

    // append the new token (GQA: head h uses kv-head h/4) on the last split
    if (split == NSPLIT - 1 && sub == 0) {
        const float4 k4 = ((const float4*)(ws + OFF_KROPE + (size_t)(b*NKV + (h>>2)) * HD))[l32];
        const float4 v4 = ((const float4*)(ws + OFF_VRAW  + (size_t)(b*NKV + (h>>2)) * HD))[l32];
        float sv = fmaf(q4.x, k4.x, fmaf(q4.y, k4.y, fmaf(q4.z, k4.z, q4.w*k4.w)));
        #pragma unroll
        for (int off = 16; off; off >>= 1) sv += __shfl_xor(sv, off, 64);
        sv *= SCALE;
        const float newm = fmaxf(m, sv);
        const float r_ = __expf(m - newm);
        const float e  = __expf(sv - newm);
        m = newm;
        l = fmaf(l, r_, e);
        acc.x = fmaf(acc.x, r_, e*v4.x);
        acc.y = fmaf(acc.y, r_, e*v4.y);
        acc.z = fmaf(acc.z, r_, e*v4.z);
        acc.w = fmaf(acc.w, r_, e*v4.w);
    }

    // merge the two half-wave online states
    const float M  = fmaxf(m, __shfl_xor(m, 32, 64));
    const float r_ = __expf(m - M);
    l *= r_; acc.x *= r_; acc.y *= r_; acc.z *= r_; acc.w *= r_;
    l     += __shfl_xor(l,     32, 64);
    acc.x += __shfl_xor(acc.x, 32, 64);
    acc.y += __shfl_xor(acc.y, 32, 64);
    acc.z += __shfl_xor(acc.z, 32, 64);
    acc.w += __shfl_xor(acc.w, 32, 64);

    if (sub == 0) {
        float* pp = ws + OFF_PART + ((size_t)pair * NSPLIT + split) * PART_STRIDE;
        ((float4*)pp)[l32] = acc;
        if (l32 == 0) { pp[HD] = M; pp[HD+1] = l; }
    }
}

// ---------------- K3: combine splits (block per (b,h))
__global__ __launch_bounds__(128) void k_combine(float* __restrict__ ws)
{
    const int pair = blockIdx.x;
    const int d = threadIdx.x;
    const float* pp = ws + OFF_PART + (size_t)pair * NSPLIT * PART_STRIDE;
    __shared__ float sm[NSPLIT], sl[NSPLIT];
    if (d < NSPLIT) { sm[d] = pp[d*PART_STRIDE + HD]; sl[d] = pp[d*PART_STRIDE + HD + 1]; }
    __syncthreads();
    float M = -1e30f;
    #pragma unroll
    for (int s = 0; s < NSPLIT; ++s) M = fmaxf(M, sm[s]);
    float L = 0.f, acc = 0.f;
    #pragma unroll 8
    for (int s = 0; s < NSPLIT; ++s) {
        const float w = expf(sm[s] - M);
        L += sl[s] * w;
        acc = fmaf(pp[s*PART_STRIDE + d], w, acc);
    }
    ws[OFF_CTX + (size_t)pair*HD + d] = acc / L;
}

// ---------------- K4: output projection (wave per row, 8-batch accum)
__global__ __launch_bounds__(256) void k_oproj(
    const float* __restrict__ Wo, const float* __restrict__ ws, float* __restrict__ out)
{
    const int wid  = threadIdx.x >> 6;
    const int lane = threadIdx.x & 63;
    const int row  = blockIdx.x * 4 + wid;   // 0..4095
    const float4* Wr = (const float4*)(Wo + (size_t)row * DD);
    const float4* C  = (const float4*)(ws + OFF_CTX);
    float acc[BB];
    #pragma unroll
    for (int b = 0; b < BB; ++b) acc[b] = 0.f;
    for (int it = 0; it < DD/256; ++it) {
        const int idx = it*64 + lane;
        const float4 w4 = ntload4(&Wr[idx]);
        #pragma unroll
        for (int b = 0; b < BB; ++b) {
            const float4 h4 = C[b*(DD/4) + idx];
            acc[b] = fmaf(w4.x, h4.x, fmaf(w4.y, h4.y, fmaf(w4.z, h4.z, fmaf(w4.w, h4.w, acc[b]))));
        }
    }
    #pragma unroll
    for (int b = 0; b < BB; ++b) {
        float v = acc[b];
        #pragma unroll
        for (int off = 32; off; off >>= 1) v += __shfl_xor(v, off, 64);
        if (lane == 0) out[(size_t)b*DD + row] = v;
    }
}

extern "C" void kernel_launch(void* const* d_in, const int* in_sizes, int n_in,
                              void* d_out, int out_size, void* d_ws, size_t ws_size,
                              hipStream_t stream)
{
    const float* hs  = (const float*)d_in[0];
    const float* pk  = (const float*)d_in[1];
    const float* pv  = (const float*)d_in[2];
    const float* Wq  = (const float*)d_in[3];
    const float* bq  = (const float*)d_in[4];
    const float* Wk  = (const float*)d_in[5];
    const float* bk  = (const float*)d_in[6];
    const float* Wv  = (const float*)d_in[7];
    const float* bv  = (const float*)d_in[8];
    const float* Wo  = (const float*)d_in[9];
    const int*   pos = (const int*)d_in[10];
    float* out = (float*)d_out;
    float* ws  = (float*)d_ws;

    k_qkv    <<<3072/4,          256, 0, stream>>>(hs, Wq, bq, Wk, bk, Wv, bv, pos, ws);
    k_attn   <<<BB*NHQ*NSPLIT/4, 256, 0, stream>>>(pk, pv, ws);
    k_combine<<<BB*NHQ,          128, 0, stream>>>(ws);
    k_oproj  <<<4096/4,          256, 0, stream>>>(Wo, ws, out);
}